// Round 1
// baseline (190.508 us; speedup 1.0000x reference)
//
#include <hip/hip_runtime.h>
#include <stdint.h>

#define B_ 2
#define N_ 120000
#define C_ 80
#define K_ 300
#define MAXDET 100
#define CAP 1024        // candidate capacity per image (mean ~150, 70 sigma headroom)
#define KTOP 300
#define NW 5            // ceil(KTOP/64)

__device__ __constant__ float SCORE_THRES_F = 0.99875f;
__device__ __constant__ float NMS_THRES_F   = 0.5f;
__device__ __constant__ float MIN_SIZE_F    = 0.001f;
__device__ __constant__ float BBOX_CLIP_F   = 4.135166556742356f; // log(1000/16) as f32

// ---------------------------------------------------------------------------
// init: zero out5 + keep flags, write labels (class id) for every slot.
// Layout of d_out (all read back as float32):
//   [0, B*CK*5)            out5   (B, C*K, 5)
//   [B*CK*5, B*CK*6)       labels (B, C*K)
//   [B*CK*6, B*CK*7)       keep   (B, C*K)
// ---------------------------------------------------------------------------
__global__ void init_out(float* __restrict__ out) {
    const int CK = C_ * K_;
    const int total = B_ * CK;          // 48000 rows
    int i = blockIdx.x * blockDim.x + threadIdx.x;
    if (i >= total) return;
    float* o5 = out + (size_t)i * 5;
    o5[0] = 0.f; o5[1] = 0.f; o5[2] = 0.f; o5[3] = 0.f; o5[4] = 0.f;
    out[(size_t)total * 5 + i] = (float)((i % CK) / K_);  // label = class id
    out[(size_t)total * 6 + i] = 0.f;                     // keep = false
}

// ---------------------------------------------------------------------------
// filter class 0: score-threshold first (only ~0.125% survive), then decode,
// clip, min-size check; compact survivors into per-image list via atomics.
// ---------------------------------------------------------------------------
__global__ void filter_c0(const float* __restrict__ boxp,
                          const float* __restrict__ clsp,
                          const float* __restrict__ anch,
                          const int* __restrict__ ih, const int* __restrict__ iw,
                          int* __restrict__ counters,
                          int* __restrict__ g_idx, float* __restrict__ g_sc,
                          float4* __restrict__ g_bx) {
#pragma clang fp contract(off)
    int t = blockIdx.x * blockDim.x + threadIdx.x;
    if (t >= B_ * N_) return;
    int b = t / N_, n = t - b * N_;
    float s = clsp[(size_t)(b * N_ + n) * C_];   // class-0 column, strided
    if (!(s > SCORE_THRES_F)) return;

    float W = (float)iw[0], H = (float)ih[0];
    float4 d = *(const float4*)(boxp + (size_t)(b * N_ + n) * 4);
    float4 a = *(const float4*)(anch + (size_t)n * 4);
    float wa = a.z - a.x, ha = a.w - a.y;
    float cxa = a.x + 0.5f * wa, cya = a.y + 0.5f * ha;
    float dw = fminf(d.z, BBOX_CLIP_F), dh = fminf(d.w, BBOX_CLIP_F);
    float cx = d.x * wa + cxa, cy = d.y * ha + cya;
    float w = expf(dw) * wa, h = expf(dh) * ha;
    float x1 = cx - 0.5f * w, y1 = cy - 0.5f * h;
    float x2 = cx + 0.5f * w, y2 = cy + 0.5f * h;
    x1 = fminf(fmaxf(x1, 0.f), W);
    y1 = fminf(fmaxf(y1, 0.f), H);
    x2 = fminf(fmaxf(x2, 0.f), W);
    y2 = fminf(fmaxf(y2, 0.f), H);
    if (!((x2 - x1 >= MIN_SIZE_F) && (y2 - y1 >= MIN_SIZE_F))) return;

    int p = atomicAdd(&counters[b], 1);
    if (p < CAP) {
        int q = b * CAP + p;
        g_idx[q] = n;
        g_sc[q]  = s;
        g_bx[q]  = make_float4(x1, y1, x2, y2);
    }
}

// ---------------------------------------------------------------------------
// sequential per-class scan: one block per image.
// Per class: gather candidates -> rank-sort (score desc, idx asc, matching
// lax.top_k tie-break) -> truncate to K -> suppression-bitmask NMS replicating
// the reference's sequential scan -> MAX_DET cap -> write kept rows at their
// sorted-rank slots -> kept set becomes next class's valid set.
// Break as soon as kept set is empty (all later classes output zeros).
// ---------------------------------------------------------------------------
__global__ __launch_bounds__(256) void seq_nms(const float* __restrict__ clsp,
                                               const int* __restrict__ counters,
                                               const int* __restrict__ g_idx,
                                               const float* __restrict__ g_sc,
                                               const float4* __restrict__ g_bx,
                                               float* __restrict__ out) {
#pragma clang fp contract(off)
    const int b   = blockIdx.x;
    const int tid = threadIdx.x;
    const int BS  = blockDim.x;

    __shared__ float  s_sc[CAP];
    __shared__ int    s_id[CAP];
    __shared__ float4 s_bx[CAP];
    __shared__ float  o_sc[KTOP];
    __shared__ int    o_id[KTOP];
    __shared__ float4 o_bx[KTOP];
    __shared__ float  o_ar[KTOP];
    __shared__ unsigned long long supp[KTOP][NW];
    __shared__ unsigned long long keepm[NW];
    __shared__ int s_cnt, s_nk;
    __shared__ int    n_id[MAXDET];
    __shared__ float4 n_bx[MAXDET];

    if (tid == 0) s_nk = 0;
    const size_t CK = (size_t)C_ * K_;

    for (int c = 0; c < C_; ++c) {
        if (c > 0 && s_nk == 0) break;   // kept set empty -> all later classes are zeros
        if (tid == 0) s_cnt = 0;
        __syncthreads();                 // A

        int m_in;
        if (c == 0) {
            int g = min(counters[b], CAP);
            for (int t = tid; t < g; t += BS) {
                int q = b * CAP + t;
                s_sc[t] = g_sc[q]; s_id[t] = g_idx[q]; s_bx[t] = g_bx[q];
            }
            __syncthreads();             // B
            m_in = g;
        } else {
            int nk = s_nk;
            for (int t = tid; t < nk; t += BS) {
                float s = clsp[(size_t)(b * N_ + n_id[t]) * C_ + c];
                if (s > SCORE_THRES_F) {
                    int p = atomicAdd(&s_cnt, 1);
                    s_sc[p] = s; s_id[p] = n_id[t]; s_bx[p] = n_bx[t];
                }
            }
            __syncthreads();             // B
            m_in = s_cnt;
        }
        int m = min(m_in, KTOP);
        if (m == 0) {
            if (tid == 0) s_nk = 0;
            __syncthreads();
            continue;
        }

        // rank-sort: unique ranks via (score desc, idx asc)
        for (int i = tid; i < m_in; i += BS) {
            float si = s_sc[i]; int di = s_id[i];
            int rank = 0;
            for (int j = 0; j < m_in; ++j) {
                float sj = s_sc[j];
                rank += (sj > si) || (sj == si && s_id[j] < di);
            }
            if (rank < KTOP) {
                float4 bx = s_bx[i];
                o_sc[rank] = si; o_id[rank] = di; o_bx[rank] = bx;
                o_ar[rank] = (bx.z - bx.x) * (bx.w - bx.y);
            }
        }
        // zero suppression rows
        for (int w = tid; w < m * NW; w += BS)
            ((unsigned long long*)supp)[w] = 0ull;
        __syncthreads();                 // C

        // suppression matrix: bit j set in row i  <=>  i<j and IoU>thres
        for (int p = tid; p < m * m; p += BS) {
            int i = p / m, j = p - i * m;
            if (j <= i) continue;
            float4 bi = o_bx[i], bj = o_bx[j];
            float lx = fmaxf(bi.x, bj.x), ly = fmaxf(bi.y, bj.y);
            float rx = fminf(bi.z, bj.z), ry = fminf(bi.w, bj.w);
            float iw_ = fmaxf(rx - lx, 0.f), ih_ = fmaxf(ry - ly, 0.f);
            float inter = iw_ * ih_;
            float iou = inter / (o_ar[i] + o_ar[j] - inter + 1e-9f);
            if (iou > NMS_THRES_F)
                atomicOr(&supp[i][j >> 6], 1ull << (j & 63));
        }
        __syncthreads();                 // D

        // sequential resolve (exact reference scan) + MAX_DET cap
        if (tid == 0) {
            unsigned long long km[NW];
            for (int w = 0; w < NW; ++w) km[w] = 0ull;
            for (int i = 0; i < m; ++i) km[i >> 6] |= 1ull << (i & 63);
            for (int i = 0; i < m; ++i)
                if ((km[i >> 6] >> (i & 63)) & 1ull)
                    for (int w = 0; w < NW; ++w) km[w] &= ~supp[i][w];
            int cnt = 0;
            for (int i = 0; i < m; ++i) {
                if ((km[i >> 6] >> (i & 63)) & 1ull) {
                    if (cnt >= MAXDET) km[i >> 6] &= ~(1ull << (i & 63));
                    else cnt++;
                }
            }
            for (int w = 0; w < NW; ++w) keepm[w] = km[w];
            s_nk = cnt;
        }
        __syncthreads();                 // E

        // write kept rows at sorted-rank slots; build next kept list
        for (int r = tid; r < m; r += BS) {
            if ((keepm[r >> 6] >> (r & 63)) & 1ull) {
                int pos = 0;
                for (int w = 0; w < (r >> 6); ++w) pos += __popcll(keepm[w]);
                pos += __popcll(keepm[r >> 6] & ((1ull << (r & 63)) - 1ull));
                size_t row = (size_t)b * CK + (size_t)c * K_ + r;
                float4 bx = o_bx[r];
                float* o5 = out + row * 5;
                o5[0] = bx.x; o5[1] = bx.y; o5[2] = bx.z; o5[3] = bx.w;
                o5[4] = o_sc[r];
                out[(size_t)B_ * CK * 6 + row] = 1.0f;   // keep flag
                n_id[pos] = o_id[r];
                n_bx[pos] = bx;
            }
        }
        // next iteration's barrier A protects n_id/n_bx reuse
    }
}

extern "C" void kernel_launch(void* const* d_in, const int* in_sizes, int n_in,
                              void* d_out, int out_size, void* d_ws, size_t ws_size,
                              hipStream_t stream) {
    const float* boxp = (const float*)d_in[0];
    const float* clsp = (const float*)d_in[1];
    const float* anch = (const float*)d_in[2];
    const int*   ih   = (const int*)d_in[3];
    const int*   iw   = (const int*)d_in[4];
    float* out = (float*)d_out;

    // workspace layout: [counters (64B)] [g_idx B*CAP int] [g_sc B*CAP f32] [g_bx B*CAP float4]
    int*    counters = (int*)d_ws;
    int*    g_idx = (int*)((char*)d_ws + 64);
    float*  g_sc  = (float*)((char*)d_ws + 64 + (size_t)B_ * CAP * 4);
    float4* g_bx  = (float4*)((char*)d_ws + 64 + (size_t)B_ * CAP * 8); // 16448: 16B aligned

    hipMemsetAsync(d_ws, 0, 64, stream);
    init_out<<<(B_ * C_ * K_ + 255) / 256, 256, 0, stream>>>(out);
    filter_c0<<<(B_ * N_ + 255) / 256, 256, 0, stream>>>(boxp, clsp, anch, ih, iw,
                                                         counters, g_idx, g_sc, g_bx);
    seq_nms<<<B_, 256, 0, stream>>>(clsp, counters, g_idx, g_sc, g_bx, out);
}

// Round 2
// 153.001 us; speedup vs baseline: 1.2451x; 1.2451x over previous
//
#include <hip/hip_runtime.h>
#include <stdint.h>

#define B_ 2
#define N_ 120000
#define C_ 80
#define K_ 300
#define MAXDET 100
#define CAP 1024        // candidate capacity per image (mean ~150)
#define KTOP 300
#define NW 5            // ceil(KTOP/64)

__device__ __constant__ float SCORE_THRES_F = 0.99875f;
__device__ __constant__ float NMS_THRES_F   = 0.5f;
__device__ __constant__ float MIN_SIZE_F    = 0.001f;
__device__ __constant__ float BBOX_CLIP_F   = 4.135166556742356f; // log(1000/16) f32

// ---------------------------------------------------------------------------
// fused init + class-0 filter.
// init: out layout (float32): [0,B*CK*5) out5 zeros | [.,B*CK*6) labels |
//       [.,B*CK*7) keep zeros.  Coalesced dword stores.
// filter: 4 strided class-0 score loads per thread (ILP), survivors (~0.125%)
//         decode+clip+minsize, atomic compaction per image.
// ---------------------------------------------------------------------------
__global__ __launch_bounds__(256) void filter_init(
    const float* __restrict__ boxp, const float* __restrict__ clsp,
    const float* __restrict__ anch, const int* __restrict__ ih,
    const int* __restrict__ iw, int* __restrict__ counters,
    int* __restrict__ g_idx, float* __restrict__ g_sc,
    float4* __restrict__ g_bx, float* __restrict__ out) {
#pragma clang fp contract(off)
    const int NT  = gridDim.x * blockDim.x;
    const int tid = blockIdx.x * blockDim.x + threadIdx.x;

    // ---- init output ----
    const int CK  = C_ * K_;
    const int L0  = B_ * CK * 5;   // 240000
    const int L1  = L0 + B_ * CK;  // 288000
    const int TOT = L1 + B_ * CK;  // 336000
    for (int i = tid; i < TOT; i += NT) {
        float v = 0.f;
        if (i >= L0 && i < L1) { int r = i - L0; v = (float)((r % CK) / K_); }
        out[i] = v;
    }

    // ---- filter class 0 ----
    const int BN = B_ * N_;
    float s[4]; int t4[4];
#pragma unroll
    for (int k = 0; k < 4; ++k) {
        int t = tid + k * NT;
        t4[k] = t;
        s[k] = (t < BN) ? clsp[(size_t)t * C_] : 0.f;   // 4 independent loads
    }
#pragma unroll
    for (int k = 0; k < 4; ++k) {
        int t = t4[k];
        if (t < BN && s[k] > SCORE_THRES_F) {
            int b = t / N_, n = t - b * N_;
            float W = (float)iw[0], H = (float)ih[0];
            float4 d = *(const float4*)(boxp + (size_t)t * 4);
            float4 a = *(const float4*)(anch + (size_t)n * 4);
            float wa = a.z - a.x, ha = a.w - a.y;
            float cxa = a.x + 0.5f * wa, cya = a.y + 0.5f * ha;
            float dw = fminf(d.z, BBOX_CLIP_F), dh = fminf(d.w, BBOX_CLIP_F);
            float cx = d.x * wa + cxa, cy = d.y * ha + cya;
            float w = expf(dw) * wa, h = expf(dh) * ha;
            float x1 = cx - 0.5f * w, y1 = cy - 0.5f * h;
            float x2 = cx + 0.5f * w, y2 = cy + 0.5f * h;
            x1 = fminf(fmaxf(x1, 0.f), W);
            y1 = fminf(fmaxf(y1, 0.f), H);
            x2 = fminf(fmaxf(x2, 0.f), W);
            y2 = fminf(fmaxf(y2, 0.f), H);
            if ((x2 - x1 >= MIN_SIZE_F) && (y2 - y1 >= MIN_SIZE_F)) {
                int p = atomicAdd(&counters[b], 1);
                if (p < CAP) {
                    int q = b * CAP + p;
                    g_idx[q] = n;
                    g_sc[q]  = s[k];
                    g_bx[q]  = make_float4(x1, y1, x2, y2);
                }
            }
        }
    }
}

// ---------------------------------------------------------------------------
// sequential per-class chain, one block per image.
// Per class: compact -> rank-sort (4x unrolled LDS scan, tie-break idx asc,
// matching lax.top_k) -> supp rows built in registers (word-segmented, no
// atomics / int-div) -> wave-0 parallel sequential resolve (lanes hold keep
// words, supp rows prefetched) -> MAX_DET cap -> write.  Next-class scores
// prefetched during rank phase so classes >=1 stay off global memory.
// ---------------------------------------------------------------------------
__global__ __launch_bounds__(256) void seq_nms(const float* __restrict__ clsp,
                                               const int* __restrict__ counters,
                                               const int* __restrict__ g_idx,
                                               const float* __restrict__ g_sc,
                                               const float4* __restrict__ g_bx,
                                               float* __restrict__ out) {
#pragma clang fp contract(off)
    const int b   = blockIdx.x;
    const int tid = threadIdx.x;
    const int BS  = blockDim.x;

    __shared__ __align__(16) float s_sc[CAP];
    __shared__ __align__(16) int   s_id[CAP];
    __shared__ float4 s_bx[CAP];
    __shared__ float  o_sc[KTOP];
    __shared__ int    o_id[KTOP];
    __shared__ float  o_ar[KTOP];
    __shared__ float  o_nsc[KTOP];
    __shared__ float4 o_bx[KTOP];
    __shared__ unsigned long long suppW[KTOP * NW];
    __shared__ unsigned long long keepm[NW];
    __shared__ int s_cnt, s_nk;
    __shared__ int    n_id[MAXDET];
    __shared__ float  n_sc[MAXDET];
    __shared__ float4 n_bx[MAXDET];

    if (tid == 0) s_nk = 0;
    const size_t CK = (size_t)C_ * K_;

    for (int c = 0; c < C_; ++c) {
        if (c > 0 && s_nk == 0) break;
        if (tid == 0) s_cnt = 0;
        __syncthreads();                 // A

        int m_in;
        if (c == 0) {
            int g = min(counters[b], CAP);
            for (int t = tid; t < g; t += BS) {
                int q = b * CAP + t;
                s_sc[t] = g_sc[q]; s_id[t] = g_idx[q]; s_bx[t] = g_bx[q];
            }
            __syncthreads();             // B
            m_in = g;
        } else {
            int nk = s_nk;
            for (int t = tid; t < nk; t += BS) {
                float sv = n_sc[t];      // prefetched last class — LDS only
                if (sv > SCORE_THRES_F) {
                    int p = atomicAdd(&s_cnt, 1);
                    s_sc[p] = sv; s_id[p] = n_id[t]; s_bx[p] = n_bx[t];
                }
            }
            __syncthreads();             // B
            m_in = s_cnt;
        }
        int m = min(m_in, KTOP);
        if (m == 0) {
            if (tid == 0) s_nk = 0;
            __syncthreads();
            continue;
        }

        // ---- R: rank-sort + next-class score prefetch ----
        for (int i = tid; i < m_in; i += BS) {
            float si = s_sc[i]; int di = s_id[i]; float4 bx = s_bx[i];
            float ns = 0.f;
            if (c + 1 < C_) ns = clsp[((size_t)(b * N_) + di) * C_ + (c + 1)];
            int rank = 0;
            int m4 = m_in & ~3;
            for (int j = 0; j < m4; j += 4) {
                float4 sj = *(const float4*)&s_sc[j];
                int4   dj = *(const int4*)&s_id[j];
                rank += (sj.x > si) || (sj.x == si && dj.x < di);
                rank += (sj.y > si) || (sj.y == si && dj.y < di);
                rank += (sj.z > si) || (sj.z == si && dj.z < di);
                rank += (sj.w > si) || (sj.w == si && dj.w < di);
            }
            for (int j = m4; j < m_in; ++j) {
                float sj = s_sc[j];
                rank += (sj > si) || (sj == si && s_id[j] < di);
            }
            if (rank < KTOP) {
                o_sc[rank] = si; o_id[rank] = di; o_bx[rank] = bx;
                o_ar[rank] = (bx.z - bx.x) * (bx.w - bx.y);
                o_nsc[rank] = ns;
            }
        }
        __syncthreads();                 // C

        // ---- S: suppression rows in registers, word-segmented ----
        for (int i = tid; i < m; i += BS) {
            float4 bi = o_bx[i]; float ai = o_ar[i];
            for (int w = 0; w < NW; ++w) {
                unsigned long long msk = 0ull;
                int jlo = max(i + 1, w * 64);
                int jhi = min(m, w * 64 + 64);
#pragma unroll 4
                for (int j = jlo; j < jhi; ++j) {
                    float4 bj = o_bx[j];
                    float lx = fmaxf(bi.x, bj.x), ly = fmaxf(bi.y, bj.y);
                    float rx = fminf(bi.z, bj.z), ry = fminf(bi.w, bj.w);
                    float ww = fmaxf(rx - lx, 0.f), hh = fmaxf(ry - ly, 0.f);
                    float inter = ww * hh;
                    float arj = (bj.z - bj.x) * (bj.w - bj.y);
                    float iou = inter / (ai + arj - inter + 1e-9f);
                    if (iou > NMS_THRES_F) msk |= 1ull << (j & 63);
                }
                suppW[i * NW + w] = msk;
            }
        }
        __syncthreads();                 // D

        // ---- V: wave-0 parallel sequential resolve + MAX_DET cap ----
        if (tid < 64) {
            int lane = tid;
            unsigned long long km = 0ull;
            if (lane < NW) {
                int nb = m - lane * 64;
                if (nb >= 64) km = ~0ull;
                else if (nb > 0) km = (1ull << nb) - 1ull;
            }
            unsigned long long srow = (lane < NW) ? suppW[lane] : 0ull;
            for (int i = 0; i < m; ++i) {
                unsigned long long nxt =
                    (lane < NW && i + 1 < m) ? suppW[(i + 1) * NW + lane] : 0ull;
                unsigned long long wv = __shfl(km, i >> 6);
                if ((wv >> (i & 63)) & 1ull) km &= ~srow;
                srow = nxt;
            }
            unsigned long long w0 = __shfl(km, 0), w1 = __shfl(km, 1),
                               w2 = __shfl(km, 2), w3 = __shfl(km, 3),
                               w4 = __shfl(km, 4);
            if (lane == 0) {
                unsigned long long arr[NW] = {w0, w1, w2, w3, w4};
                int cnt = 0;
                for (int w = 0; w < NW; ++w) {
                    unsigned long long x = arr[w];
                    if (cnt >= MAXDET) { arr[w] = 0ull; continue; }
                    int pc = __popcll(x);
                    if (cnt + pc > MAXDET) {
                        int need = MAXDET - cnt;
                        unsigned long long y = x;
                        for (int k2 = 0; k2 < need; ++k2) y &= y - 1ull;
                        arr[w] = x ^ y;   // lowest `need` set bits
                        cnt = MAXDET;
                    } else cnt += pc;
                }
                int tot = 0;
                for (int w = 0; w < NW; ++w) { keepm[w] = arr[w]; tot += __popcll(arr[w]); }
                s_nk = tot;
            }
        }
        __syncthreads();                 // E

        // ---- W: write kept rows + build next kept list ----
        for (int r = tid; r < m; r += BS) {
            unsigned long long wv = keepm[r >> 6];
            if ((wv >> (r & 63)) & 1ull) {
                int pos = __popcll(wv & ((1ull << (r & 63)) - 1ull));
                for (int w = 0; w < (r >> 6); ++w) pos += __popcll(keepm[w]);
                size_t row = (size_t)b * CK + (size_t)c * K_ + r;
                float4 bx = o_bx[r];
                float* o5 = out + row * 5;
                o5[0] = bx.x; o5[1] = bx.y; o5[2] = bx.z; o5[3] = bx.w;
                o5[4] = o_sc[r];
                out[(size_t)B_ * CK * 6 + row] = 1.0f;
                n_id[pos] = o_id[r];
                n_bx[pos] = bx;
                n_sc[pos] = o_nsc[r];
            }
        }
        // next iteration's barrier A protects n_* reuse
    }
}

extern "C" void kernel_launch(void* const* d_in, const int* in_sizes, int n_in,
                              void* d_out, int out_size, void* d_ws, size_t ws_size,
                              hipStream_t stream) {
    const float* boxp = (const float*)d_in[0];
    const float* clsp = (const float*)d_in[1];
    const float* anch = (const float*)d_in[2];
    const int*   ih   = (const int*)d_in[3];
    const int*   iw   = (const int*)d_in[4];
    float* out = (float*)d_out;

    // ws: [counters 64B] [g_idx B*CAP i32] [g_sc B*CAP f32] [g_bx B*CAP f4]
    int*    counters = (int*)d_ws;
    int*    g_idx = (int*)((char*)d_ws + 64);
    float*  g_sc  = (float*)((char*)d_ws + 64 + (size_t)B_ * CAP * 4);
    float4* g_bx  = (float4*)((char*)d_ws + 64 + (size_t)B_ * CAP * 8);

    hipMemsetAsync(d_ws, 0, 64, stream);
    // 235 blocks * 256 threads = 60160 threads; 4 score rows each covers 240k
    filter_init<<<235, 256, 0, stream>>>(boxp, clsp, anch, ih, iw,
                                         counters, g_idx, g_sc, g_bx, out);
    seq_nms<<<B_, 256, 0, stream>>>(clsp, counters, g_idx, g_sc, g_bx, out);
}

// Round 3
// 149.759 us; speedup vs baseline: 1.2721x; 1.0216x over previous
//
#include <hip/hip_runtime.h>
#include <stdint.h>

#define B_ 2
#define N_ 120000
#define C_ 80
#define K_ 300
#define MAXDET 100
#define CAP 1024        // per-image candidate capacity in LDS (mean ~150)
#define KTOP 300
#define NW 5            // ceil(KTOP/64)
#define NB 235          // filter blocks
#define TPB 256
#define SLOTS 32        // per-(image,block) slot capacity; mean ~0.64 survivors

__device__ __constant__ float SCORE_THRES_F = 0.99875f;
__device__ __constant__ float NMS_THRES_F   = 0.5f;
__device__ __constant__ float MIN_SIZE_F    = 0.001f;
__device__ __constant__ float BBOX_CLIP_F   = 4.135166556742356f; // log(1000/16) f32

// ---------------------------------------------------------------------------
// fused init + class-0 filter, poison-proof (no global counter init needed):
// each block compacts its survivors into a PRIVATE slot region via an LDS
// counter and writes its count unconditionally. No memset node, no global
// atomics. Score loads issued before the init loop to hide HBM latency.
// out layout (f32): [0,B*CK*5) out5 | [.,B*CK*6) labels | [.,B*CK*7) keep.
// ---------------------------------------------------------------------------
__global__ __launch_bounds__(TPB) void filter_init(
    const float* __restrict__ boxp, const float* __restrict__ clsp,
    const float* __restrict__ anch, const int* __restrict__ ih,
    const int* __restrict__ iw, int* __restrict__ cnt,
    int* __restrict__ g_idx, float* __restrict__ g_sc,
    float4* __restrict__ g_bx, float* __restrict__ out) {
#pragma clang fp contract(off)
    __shared__ int lcnt[2];
    const int blk = blockIdx.x;
    const int ltid = threadIdx.x;
    const int NT  = NB * TPB;            // 60160
    const int tid = blk * TPB + ltid;
    if (ltid < 2) lcnt[ltid] = 0;

    // ---- issue the 4 strided class-0 score loads first (ILP) ----
    const int BN = B_ * N_;
    float s[4]; int t4[4];
#pragma unroll
    for (int k = 0; k < 4; ++k) {
        int t = tid + k * NT;
        t4[k] = t;
        s[k] = (t < BN) ? clsp[(size_t)t * C_] : 0.f;
    }

    // ---- init output (coalesced), overlaps the loads above ----
    const int CK  = C_ * K_;
    const int L0  = B_ * CK * 5;   // 240000
    const int L1  = L0 + B_ * CK;  // 288000
    const int TOT = L1 + B_ * CK;  // 336000
    for (int i = tid; i < TOT; i += NT) {
        float v = 0.f;
        if (i >= L0 && i < L1) { int r = i - L0; v = (float)((r % CK) / K_); }
        out[i] = v;
    }
    __syncthreads();   // lcnt ready

    // ---- decode + compact survivors into block-private slots ----
#pragma unroll
    for (int k = 0; k < 4; ++k) {
        int t = t4[k];
        if (t < BN && s[k] > SCORE_THRES_F) {
            int b = t / N_, n = t - b * N_;
            float W = (float)iw[0], H = (float)ih[0];
            float4 d = *(const float4*)(boxp + (size_t)t * 4);
            float4 a = *(const float4*)(anch + (size_t)n * 4);
            float wa = a.z - a.x, ha = a.w - a.y;
            float cxa = a.x + 0.5f * wa, cya = a.y + 0.5f * ha;
            float dw = fminf(d.z, BBOX_CLIP_F), dh = fminf(d.w, BBOX_CLIP_F);
            float cx = d.x * wa + cxa, cy = d.y * ha + cya;
            float w = expf(dw) * wa, h = expf(dh) * ha;
            float x1 = cx - 0.5f * w, y1 = cy - 0.5f * h;
            float x2 = cx + 0.5f * w, y2 = cy + 0.5f * h;
            x1 = fminf(fmaxf(x1, 0.f), W);
            y1 = fminf(fmaxf(y1, 0.f), H);
            x2 = fminf(fmaxf(x2, 0.f), W);
            y2 = fminf(fmaxf(y2, 0.f), H);
            if ((x2 - x1 >= MIN_SIZE_F) && (y2 - y1 >= MIN_SIZE_F)) {
                int p = atomicAdd(&lcnt[b], 1);   // LDS atomic, block-local
                if (p < SLOTS) {
                    int q = (b * NB + blk) * SLOTS + p;
                    g_idx[q] = n;
                    g_sc[q]  = s[k];
                    g_bx[q]  = make_float4(x1, y1, x2, y2);
                }
            }
        }
    }
    __syncthreads();
    if (ltid < 2) cnt[ltid * NB + blk] = min(lcnt[ltid], SLOTS);  // unconditional
}

// ---------------------------------------------------------------------------
// sequential per-class chain, one block per image.
// Class 0 gathers candidates from per-block slot regions via a shfl prefix
// scan over the 235 counts. Then per class: rank-sort (4x unrolled LDS scan,
// tie-break idx asc, matching lax.top_k) -> supp rows in registers (word-
// segmented) -> wave-0 parallel sequential resolve -> MAX_DET cap -> write.
// Next-class scores prefetched during rank phase.
// ---------------------------------------------------------------------------
__global__ __launch_bounds__(TPB) void seq_nms(const float* __restrict__ clsp,
                                               const int* __restrict__ cnt,
                                               const int* __restrict__ g_idx,
                                               const float* __restrict__ g_sc,
                                               const float4* __restrict__ g_bx,
                                               float* __restrict__ out) {
#pragma clang fp contract(off)
    const int b   = blockIdx.x;
    const int tid = threadIdx.x;
    const int BS  = blockDim.x;

    __shared__ __align__(16) float s_sc[CAP];
    __shared__ __align__(16) int   s_id[CAP];
    __shared__ float4 s_bx[CAP];
    __shared__ float  o_sc[KTOP];
    __shared__ int    o_id[KTOP];
    __shared__ float  o_ar[KTOP];
    __shared__ float  o_nsc[KTOP];
    __shared__ float4 o_bx[KTOP];
    __shared__ unsigned long long suppW[KTOP * NW];
    __shared__ unsigned long long keepm[NW];
    __shared__ int s_cnt, s_nk, s_m;
    __shared__ int wsum[4];
    __shared__ int    n_id[MAXDET];
    __shared__ float  n_sc[MAXDET];
    __shared__ float4 n_bx[MAXDET];

    if (tid == 0) s_nk = 0;
    const size_t CK = (size_t)C_ * K_;

    for (int c = 0; c < C_; ++c) {
        if (c > 0 && s_nk == 0) break;
        if (tid == 0) s_cnt = 0;
        __syncthreads();                 // A

        int m_in;
        if (c == 0) {
            // ---- prefix-scan the 235 per-block counts, then gather ----
            int lane = tid & 63, wvi = tid >> 6;
            int v = (tid < NB) ? cnt[b * NB + tid] : 0;
            int x = v;
            for (int d = 1; d < 64; d <<= 1) {
                int y = __shfl_up(x, d);
                if (lane >= d) x += y;
            }
            if (lane == 63) wsum[wvi] = x;
            __syncthreads();
            int offbase = 0;
            for (int w = 0; w < wvi; ++w) offbase += wsum[w];
            if (tid == BS - 1) s_m = offbase + x;   // grand total
            int excl = offbase + x - v;             // exclusive prefix
            for (int j = 0; j < v; ++j) {
                int dst = excl + j;
                if (dst < CAP) {
                    int src = (b * NB + tid) * SLOTS + j;
                    s_sc[dst] = g_sc[src];
                    s_id[dst] = g_idx[src];
                    s_bx[dst] = g_bx[src];
                }
            }
            __syncthreads();             // B
            m_in = min(s_m, CAP);
        } else {
            int nk = s_nk;
            for (int t = tid; t < nk; t += BS) {
                float sv = n_sc[t];      // prefetched last class — LDS only
                if (sv > SCORE_THRES_F) {
                    int p = atomicAdd(&s_cnt, 1);
                    s_sc[p] = sv; s_id[p] = n_id[t]; s_bx[p] = n_bx[t];
                }
            }
            __syncthreads();             // B
            m_in = s_cnt;
        }
        int m = min(m_in, KTOP);
        if (m == 0) {
            if (tid == 0) s_nk = 0;
            __syncthreads();
            continue;
        }

        // ---- R: rank-sort + next-class score prefetch ----
        for (int i = tid; i < m_in; i += BS) {
            float si = s_sc[i]; int di = s_id[i]; float4 bx = s_bx[i];
            float ns = 0.f;
            if (c + 1 < C_) ns = clsp[((size_t)(b * N_) + di) * C_ + (c + 1)];
            int rank = 0;
            int m4 = m_in & ~3;
            for (int j = 0; j < m4; j += 4) {
                float4 sj = *(const float4*)&s_sc[j];
                int4   dj = *(const int4*)&s_id[j];
                rank += (sj.x > si) || (sj.x == si && dj.x < di);
                rank += (sj.y > si) || (sj.y == si && dj.y < di);
                rank += (sj.z > si) || (sj.z == si && dj.z < di);
                rank += (sj.w > si) || (sj.w == si && dj.w < di);
            }
            for (int j = m4; j < m_in; ++j) {
                float sj = s_sc[j];
                rank += (sj > si) || (sj == si && s_id[j] < di);
            }
            if (rank < KTOP) {
                o_sc[rank] = si; o_id[rank] = di; o_bx[rank] = bx;
                o_ar[rank] = (bx.z - bx.x) * (bx.w - bx.y);
                o_nsc[rank] = ns;
            }
        }
        __syncthreads();                 // C

        // ---- S: suppression rows in registers, word-segmented ----
        for (int i = tid; i < m; i += BS) {
            float4 bi = o_bx[i]; float ai = o_ar[i];
            for (int w = 0; w < NW; ++w) {
                unsigned long long msk = 0ull;
                int jlo = max(i + 1, w * 64);
                int jhi = min(m, w * 64 + 64);
#pragma unroll 4
                for (int j = jlo; j < jhi; ++j) {
                    float4 bj = o_bx[j];
                    float lx = fmaxf(bi.x, bj.x), ly = fmaxf(bi.y, bj.y);
                    float rx = fminf(bi.z, bj.z), ry = fminf(bi.w, bj.w);
                    float ww = fmaxf(rx - lx, 0.f), hh = fmaxf(ry - ly, 0.f);
                    float inter = ww * hh;
                    float arj = (bj.z - bj.x) * (bj.w - bj.y);
                    float iou = inter / (ai + arj - inter + 1e-9f);
                    if (iou > NMS_THRES_F) msk |= 1ull << (j & 63);
                }
                suppW[i * NW + w] = msk;
            }
        }
        __syncthreads();                 // D

        // ---- V: wave-0 parallel sequential resolve + MAX_DET cap ----
        if (tid < 64) {
            int lane = tid;
            unsigned long long km = 0ull;
            if (lane < NW) {
                int nb = m - lane * 64;
                if (nb >= 64) km = ~0ull;
                else if (nb > 0) km = (1ull << nb) - 1ull;
            }
            unsigned long long srow = (lane < NW) ? suppW[lane] : 0ull;
            for (int i = 0; i < m; ++i) {
                unsigned long long nxt =
                    (lane < NW && i + 1 < m) ? suppW[(i + 1) * NW + lane] : 0ull;
                unsigned long long wv = __shfl(km, i >> 6);
                if ((wv >> (i & 63)) & 1ull) km &= ~srow;
                srow = nxt;
            }
            unsigned long long w0 = __shfl(km, 0), w1 = __shfl(km, 1),
                               w2 = __shfl(km, 2), w3 = __shfl(km, 3),
                               w4 = __shfl(km, 4);
            if (lane == 0) {
                unsigned long long arr[NW] = {w0, w1, w2, w3, w4};
                int cnt2 = 0;
                for (int w = 0; w < NW; ++w) {
                    unsigned long long x = arr[w];
                    if (cnt2 >= MAXDET) { arr[w] = 0ull; continue; }
                    int pc = __popcll(x);
                    if (cnt2 + pc > MAXDET) {
                        int need = MAXDET - cnt2;
                        unsigned long long y = x;
                        for (int k2 = 0; k2 < need; ++k2) y &= y - 1ull;
                        arr[w] = x ^ y;   // lowest `need` set bits
                        cnt2 = MAXDET;
                    } else cnt2 += pc;
                }
                int tot = 0;
                for (int w = 0; w < NW; ++w) { keepm[w] = arr[w]; tot += __popcll(arr[w]); }
                s_nk = tot;
            }
        }
        __syncthreads();                 // E

        // ---- W: write kept rows + build next kept list ----
        for (int r = tid; r < m; r += BS) {
            unsigned long long wv = keepm[r >> 6];
            if ((wv >> (r & 63)) & 1ull) {
                int pos = __popcll(wv & ((1ull << (r & 63)) - 1ull));
                for (int w = 0; w < (r >> 6); ++w) pos += __popcll(keepm[w]);
                size_t row = (size_t)b * CK + (size_t)c * K_ + r;
                float4 bx = o_bx[r];
                float* o5 = out + row * 5;
                o5[0] = bx.x; o5[1] = bx.y; o5[2] = bx.z; o5[3] = bx.w;
                o5[4] = o_sc[r];
                out[(size_t)B_ * CK * 6 + row] = 1.0f;
                n_id[pos] = o_id[r];
                n_bx[pos] = bx;
                n_sc[pos] = o_nsc[r];
            }
        }
        // next iteration's barrier A protects n_* reuse
    }
}

extern "C" void kernel_launch(void* const* d_in, const int* in_sizes, int n_in,
                              void* d_out, int out_size, void* d_ws, size_t ws_size,
                              hipStream_t stream) {
    const float* boxp = (const float*)d_in[0];
    const float* clsp = (const float*)d_in[1];
    const float* anch = (const float*)d_in[2];
    const int*   ih   = (const int*)d_in[3];
    const int*   iw   = (const int*)d_in[4];
    float* out = (float*)d_out;

    // ws layout (no zeroing required — every used word is written each call):
    //   [0, 4096)                       cnt[B_][NB]   (2*235 ints)
    //   [4096, +60160)                  g_idx  B_*NB*SLOTS i32
    //   [64256, +60160)                 g_sc   B_*NB*SLOTS f32
    //   [124416, +240640)               g_bx   B_*NB*SLOTS float4 (16B-aligned)
    int*    cnt   = (int*)d_ws;
    int*    g_idx = (int*)((char*)d_ws + 4096);
    float*  g_sc  = (float*)((char*)d_ws + 4096 + (size_t)B_ * NB * SLOTS * 4);
    float4* g_bx  = (float4*)((char*)d_ws + 4096 + (size_t)B_ * NB * SLOTS * 8);

    filter_init<<<NB, TPB, 0, stream>>>(boxp, clsp, anch, ih, iw,
                                        cnt, g_idx, g_sc, g_bx, out);
    seq_nms<<<B_, TPB, 0, stream>>>(clsp, cnt, g_idx, g_sc, g_bx, out);
}